// Round 8
// baseline (268.788 us; speedup 1.0000x reference)
//
#include <hip/hip_runtime.h>
#include <hip/hip_bf16.h>

// Problem: MultiHeadAttention  B=2,S=2048,E=1024,H=16,D=64
// R12: (a) attn restored to R9-exact (512x512, 16 q-rows/wave, dbuf K/V,
//     one barrier/tile, ~42us proven; R11's 32-row waves halved occupancy
//     27->12.7% and lost 10.7us). cvtpk kept (validated R10/R11).
//     (b) GEMM core experiment: LDS double-buffer + reg prefetch + ONE
//     barrier per K-step, with __launch_bounds__(256,2) so the 8 live uint4
//     (32 VGPR) do NOT spill (R6's failure: compiler capped at 84 VGPR ->
//     390MB scratch). LDS 73.7KB/block -> 2 blocks/CU.
//     (c) prep_wcat + f32-fold staging kept (neutral, fewer launches).

typedef __attribute__((ext_vector_type(4))) float  f32x4;
typedef __attribute__((ext_vector_type(8))) short  bf16x8;

#define S_LEN 2048
#define EMB   1024
#define NH    16
#define HD    64

#define LDSW 72   // 64 + 8 pad: 144B row stride -- KEEP multiple of 8 shorts
                  // (16B) or every ds_*_b128 goes through the misaligned slow
                  // path (R8: 3x slowdown, zero reported conflicts).

// q pre-scale folds 1/sqrt(64) and log2(e):  0.125 * 1.4426950408889634
#define QSCALE 0.18033688011112042f

#if __has_builtin(__builtin_amdgcn_exp2f)
#define EXP2(x) __builtin_amdgcn_exp2f(x)
#else
#define EXP2(x) __exp2f(x)
#endif

__device__ __forceinline__ unsigned short f2bf(float f) {
    __hip_bfloat16 h = __float2bfloat16(f);
    return __builtin_bit_cast(unsigned short, h);
}
// HW packed cvt f32x2 -> bf16x2 (RNE), gfx950: no builtin, asm only.
// D[15:0]=bf16(lo), D[31:16]=bf16(hi)  => memory order lo,hi.
__device__ __forceinline__ unsigned int cvtpk(float lo, float hi) {
    unsigned int r;
    asm("v_cvt_pk_bf16_f32 %0, %1, %2" : "=v"(r) : "v"(lo), "v"(hi));
    return r;
}

// ---------------- prep: wcat build only ----------------
// wcat[n][e] (n = qkv*1024 + h*64 + d)  <-  w{q,k,v}[h][e][d]
__global__ __launch_bounds__(256) void prep_wcat(const float* __restrict__ wq,
                                                 const float* __restrict__ wk,
                                                 const float* __restrict__ wv,
                                                 unsigned short* __restrict__ wcat) {
    int blk = blockIdx.x;
    int et  = blk & 7;
    int h   = (blk >> 3) & 15;
    int qkv = blk >> 7;
    const float* w = (qkv == 0) ? wq : (qkv == 1) ? wk : wv;
    int t = threadIdx.x;
    int d = t & 63, es = t >> 6;
    int e0 = et * 128 + es * 32;

    unsigned short val[32];
    #pragma unroll
    for (int i = 0; i < 32; i++)
        val[i] = f2bf(w[(size_t)h * 65536 + (size_t)(e0 + i) * 64 + d]);

    size_t n = (size_t)qkv * 1024 + h * 64 + d;
    #pragma unroll
    for (int k = 0; k < 4; k++)
        *(uint4*)(wcat + n * 1024 + e0 + k * 8) = *(const uint4*)(val + k * 8);
}

// ---------------- GEMM core: C[128x128] = A[M,K] * Bt[N,K]^T, fp32 acc ----
// LDS double-buffer (4 x [128][72] regions: A0,B0,A1,B1), register prefetch,
// ONE barrier per K-step. Hazard: barrier at iter k proves the readers of
// buf[(k+1)&1] (iter k-1's compute) are done before it is overwritten.
// AF32/BF32: operand is row-major f32, converted to bf16 at prefetch time.
template<int AF32, int BF32>
__device__ __forceinline__ void gemm_tile_core(const void* __restrict__ Av,
                                               const void* __restrict__ Btv,
                                               int K, int m0, int n0,
                                               unsigned short* S,   // 4*128*LDSW shorts
                                               f32x4 acc[4][4]) {
    const int t    = threadIdx.x;
    const int wave = t >> 6, lane = t & 63;
    const int wm   = (wave >> 1) * 64, wn = (wave & 1) * 64;
    const int lr   = lane & 15, quad = lane >> 4;
    const int sr   = t >> 3;             // 0..31
    const int sc   = (t & 7) * 8;        // col (elements)

    unsigned short* As[2] = { S,                 S + 2 * 128 * LDSW };
    unsigned short* Bs[2] = { S + 128 * LDSW,    S + 3 * 128 * LDSW };

    #pragma unroll
    for (int i = 0; i < 4; i++)
        #pragma unroll
        for (int j = 0; j < 4; j++) acc[i][j] = (f32x4)(0.0f);

    uint4 a[4], b[4];
    // LOAD tile at k0 into a/b (with inline f32->bf16 cvt where needed)
    #define GLOAD(k0)                                                              \
        _Pragma("unroll")                                                          \
        for (int p = 0; p < 4; ++p) {                                              \
            int r = p * 32 + sr;                                                   \
            if (AF32) {                                                            \
                const float* Af = (const float*)Av + (size_t)(m0 + r) * K + (k0) + sc; \
                float4 v0 = *(const float4*)Af;                                    \
                float4 v1 = *(const float4*)(Af + 4);                              \
                a[p].x = cvtpk(v0.x, v0.y); a[p].y = cvtpk(v0.z, v0.w);            \
                a[p].z = cvtpk(v1.x, v1.y); a[p].w = cvtpk(v1.z, v1.w);            \
            } else {                                                               \
                a[p] = *(const uint4*)((const unsigned short*)Av + (size_t)(m0 + r) * K + (k0) + sc); \
            }                                                                      \
            if (BF32) {                                                            \
                const float* Bf = (const float*)Btv + (size_t)(n0 + r) * K + (k0) + sc; \
                float4 v0 = *(const float4*)Bf;                                    \
                float4 v1 = *(const float4*)(Bf + 4);                              \
                b[p].x = cvtpk(v0.x, v0.y); b[p].y = cvtpk(v0.z, v0.w);            \
                b[p].z = cvtpk(v1.x, v1.y); b[p].w = cvtpk(v1.z, v1.w);            \
            } else {                                                               \
                b[p] = *(const uint4*)((const unsigned short*)Btv + (size_t)(n0 + r) * K + (k0) + sc); \
            }                                                                      \
        }
    #define SSTORE(buf)                                                            \
        _Pragma("unroll")                                                          \
        for (int p = 0; p < 4; ++p) {                                              \
            int r = p * 32 + sr;                                                   \
            *(uint4*)(As[buf] + r * LDSW + sc) = a[p];                             \
            *(uint4*)(Bs[buf] + r * LDSW + sc) = b[p];                             \
        }

    // prologue: tile 0 -> buf0 (visible after first barrier); tile 1 -> regs
    GLOAD(0);
    SSTORE(0);
    if (K > 64) { GLOAD(64); }

    for (int k0 = 0; k0 < K; k0 += 64) {
        __syncthreads();                 // buf[cur] visible; buf[cur^1] readers done
        const int cur = (k0 >> 6) & 1;
        if (k0 + 64 < K) {
            SSTORE(cur ^ 1);             // stage next tile (regs -> other buffer)
            if (k0 + 128 < K) { GLOAD(k0 + 128); }   // prefetch tile+2
        }
        const unsigned short* Ac = As[cur];
        const unsigned short* Bc = Bs[cur];
        #pragma unroll
        for (int kk = 0; kk < 64; kk += 32) {
            bf16x8 af[4], bfr[4];
            #pragma unroll
            for (int i = 0; i < 4; i++)
                af[i] = *(const bf16x8*)(Ac + (wm + i * 16 + lr) * LDSW + kk + quad * 8);
            #pragma unroll
            for (int j = 0; j < 4; j++)
                bfr[j] = *(const bf16x8*)(Bc + (wn + j * 16 + lr) * LDSW + kk + quad * 8);
            #pragma unroll
            for (int i = 0; i < 4; i++)
                #pragma unroll
                for (int j = 0; j < 4; j++)
                    acc[i][j] = __builtin_amdgcn_mfma_f32_16x16x32_bf16(af[i], bfr[j], acc[i][j], 0, 0, 0);
        }
    }
    #undef GLOAD
    #undef SSTORE
}

// GEMM1: QKV = x(f32) * Wcat.
//   Q (scaled) -> qb[bh][s][d], K -> kb[bh][s][d]  (both via LDS roundtrip, b128 out)
//   V -> LDS-transpose -> vt[bh][d][s] (b128 out)
__global__ __launch_bounds__(256, 2) void gemm_qkv(const float* __restrict__ x,
                                                   const unsigned short* __restrict__ wcat,
                                                   unsigned short* __restrict__ qb,
                                                   unsigned short* __restrict__ kb,
                                                   unsigned short* __restrict__ vt) {
    __shared__ unsigned short Smem[4 * 128 * LDSW];   // 73728B dbuf; Tb needs 34816B
    f32x4 acc[4][4];
    int m0 = blockIdx.x * 128, n0 = blockIdx.y * 128;
    gemm_tile_core<1, 0>(x, wcat, EMB, m0, n0, Smem, acc);

    int t = threadIdx.x, wave = t >> 6, lane = t & 63;
    int wm = (wave >> 1) * 64, wn = (wave & 1) * 64, lr = lane & 15, quad = lane >> 4;
    int b  = m0 >> 11;
    int s0 = m0 & 2047;
    unsigned short* Tb = Smem;                 // reuse: [128][136]

    if (n0 < 2048) {
        bool isQ = (n0 < 1024);
        unsigned short* dst = isQ ? qb : kb;
        float sc = isQ ? QSCALE : 1.0f;
        __syncthreads();                       // done reading LDS tiles
        #pragma unroll
        for (int i = 0; i < 4; i++)
            #pragma unroll
            for (int j = 0; j < 4; j++)
                #pragma unroll
                for (int e = 0; e < 4; e++)
                    Tb[(wm + i * 16 + quad * 4 + e) * 136 + wn + j * 16 + lr] = f2bf(acc[i][j][e] * sc);
        __syncthreads();
        #pragma unroll
        for (int p = 0; p < 8; p++) {
            int r  = p * 16 + (t >> 4);
            int ch = (t & 15) * 8;
            int n  = n0 + ch;
            int h  = (n >> 6) & 15, d = ch & 63;
            *(uint4*)(dst + (((size_t)(b * NH + h)) * S_LEN + s0 + r) * HD + d) =
                *(const uint4*)(Tb + r * 136 + ch);
        }
    } else {
        // V: transpose in LDS, then coalesced rows of vt[bh][d][s]
        __syncthreads();
        #pragma unroll
        for (int i = 0; i < 4; i++)
            #pragma unroll
            for (int j = 0; j < 4; j++)
                #pragma unroll
                for (int e = 0; e < 4; e++)
                    Tb[(wn + j * 16 + lr) * 136 + (wm + i * 16 + quad * 4 + e)] = f2bf(acc[i][j][e]);
        __syncthreads();
        #pragma unroll
        for (int p = 0; p < 8; p++) {
            int nl  = p * 16 + (t >> 4);
            int n   = n0 + nl;
            int h   = (n >> 6) & 15, d = n & 63;
            int col = (t & 15) * 8;
            *(uint4*)(vt + (((size_t)(b * NH + h)) * HD + d) * S_LEN + s0 + col) =
                *(const uint4*)(Tb + nl * 136 + col);
        }
    }
}

// GEMM2: out = ao * w_proj(f32)^T + b
__global__ __launch_bounds__(256, 2) void gemm_proj(const unsigned short* __restrict__ ao,
                                                    const float* __restrict__ wproj,
                                                    const float* __restrict__ bproj,
                                                    float* __restrict__ out) {
    __shared__ unsigned short Smem[4 * 128 * LDSW];
    f32x4 acc[4][4];
    int m0 = blockIdx.x * 128, n0 = blockIdx.y * 128;
    gemm_tile_core<0, 1>(ao, wproj, EMB, m0, n0, Smem, acc);

    int t = threadIdx.x, wave = t >> 6, lane = t & 63;
    int wm = (wave >> 1) * 64, wn = (wave & 1) * 64, lr = lane & 15, quad = lane >> 4;
    #pragma unroll
    for (int i = 0; i < 4; i++)
        #pragma unroll
        for (int j = 0; j < 4; j++) {
            int n = n0 + wn + j * 16 + lr;
            float bias = bproj[n];
            #pragma unroll
            for (int e = 0; e < 4; e++) {
                int m = m0 + wm + i * 16 + quad * 4 + e;
                out[(size_t)m * EMB + n] = acc[i][j][e] + bias;
            }
        }
}

// ---------------- MFMA flash attention, causal, S^T-swapped ----------------
// R9-exact: 512 blocks x 512 threads = 32 bh x 16 chunks of 128 rows; 8 waves
// x 16 rows. Heavy-first chunk order: CU hosts blocks c & c+256 = chunks
// {15-g, g} -> constant 34 tiles per CU. Double-buffered K/V LDS: ONE barrier
// per tile. Softmax: exp2(S) raw (constant exponent bias cancels in O/l);
// l via MFMA-vs-ones; P->bf16 via v_cvt_pk_bf16_f32.
__global__ __launch_bounds__(512) void attn_mfma(const unsigned short* __restrict__ qb,
                                                 const unsigned short* __restrict__ kb,
                                                 const unsigned short* __restrict__ vtb,
                                                 unsigned short* __restrict__ ao) {
    __shared__ unsigned short Ks[2][64 * LDSW];     // [buf][key][d]
    __shared__ unsigned short Vs[2][64 * LDSW];     // [buf][d][key]
    __shared__ unsigned short Ps[128 * LDSW];       // 8 waves x 16 rows [q][key]; reused as O buffer

    int bIdx = blockIdx.x;
    int bh   = bIdx & 31;
    int grp  = bIdx >> 5;
    int chunk = (grp < 8) ? (15 - grp) : (grp - 8);   // heavy chunks first
    int b = bh >> 4, h = bh & 15;
    int t = threadIdx.x, wave = t >> 6, lane = t & 63;
    int c = lane & 15, quad = lane >> 4;

    const unsigned short* Q  = qb  + (size_t)bh * S_LEN * HD;
    const unsigned short* K  = kb  + (size_t)bh * S_LEN * HD;
    const unsigned short* Vt = vtb + (size_t)bh * HD * S_LEN;

    int r0 = chunk * 128;
    int rw = r0 + wave * 16;                 // wave's 16 q rows

    // Q frags (B-operand): B[n=q=c][k=d]
    bf16x8 Qf[2];
    #pragma unroll
    for (int ks = 0; ks < 2; ks++)
        Qf[ks] = *(const bf16x8*)(Q + (size_t)(rw + c) * HD + ks * 32 + quad * 8);

    f32x4 O[4];
    f32x4 lacc = (f32x4)(0.0f);
    #pragma unroll
    for (int dt = 0; dt < 4; dt++) O[dt] = (f32x4)(0.0f);

    const short oneb = (short)0x3F80;
    bf16x8 ones = {oneb, oneb, oneb, oneb, oneb, oneb, oneb, oneb};

    unsigned short* Pw = Ps + wave * 16 * LDSW;
    int sr = t >> 3, scg = (t & 7) * 8;      // 512 thr: sr 0..63

    int NT = (r0 + 128) >> 6;                // tiles this block computes (>= 2)

    // prologue: stage tile 0 directly, load tile 1 into regs
    uint4 kpre = *(const uint4*)(K  + (size_t)sr * HD + scg);
    uint4 vpre = *(const uint4*)(Vt + (size_t)sr * S_LEN + scg);
    *(uint4*)(Ks[0] + sr * LDSW + scg) = kpre;
    *(uint4*)(Vs[0] + sr * LDSW + scg) = vpre;
    kpre = *(const uint4*)(K  + (size_t)(64 + sr) * HD + scg);
    vpre = *(const uint4*)(Vt + (size_t)sr * S_LEN + 64 + scg);

    for (int tt = 0; tt < NT; ++tt) {
        __syncthreads();   // tile tt visible; tile tt-1 readers done
        if (tt + 1 < NT) {
            unsigned short* Kd = Ks[(tt + 1) & 1];
            unsigned short* Vd = Vs[(tt + 1) & 1];
            *(uint4*)(Kd + sr * LDSW + scg) = kpre;
            *(uint4*)(Vd + sr * LDSW + scg) = vpre;
            if (tt + 2 < NT) {
                kpre = *(const uint4*)(K  + (size_t)((tt + 2) * 64 + sr) * HD + scg);
                vpre = *(const uint4*)(Vt + (size_t)sr * S_LEN + (tt + 2) * 64 + scg);
            }
        }
        int j0 = tt << 6;
        if (j0 <= rw + 15) {
            const unsigned short* Kc = Ks[tt & 1];
            const unsigned short* Vc = Vs[tt & 1];

            // S^T = K Q^T : D[m=key][n=q]
            f32x4 S4[4];
            #pragma unroll
            for (int kt = 0; kt < 4; kt++) S4[kt] = (f32x4)(0.0f);
            __builtin_amdgcn_s_setprio(1);
            #pragma unroll
            for (int ks = 0; ks < 2; ks++) {
                bf16x8 Kf[4];
                #pragma unroll
                for (int kt = 0; kt < 4; kt++)
                    Kf[kt] = *(const bf16x8*)(Kc + (kt * 16 + c) * LDSW + ks * 32 + quad * 8);
                #pragma unroll
                for (int kt = 0; kt < 4; kt++)
                    S4[kt] = __builtin_amdgcn_mfma_f32_16x16x32_bf16(Kf[kt], Qf[ks], S4[kt], 0, 0, 0);
            }
            __builtin_amdgcn_s_setprio(0);

            bool need_mask = (j0 + 63 > rw);
            #pragma unroll
            for (int kt = 0; kt < 4; kt++) {
                float p0 = EXP2(S4[kt][0]);
                float p1 = EXP2(S4[kt][1]);
                float p2 = EXP2(S4[kt][2]);
                float p3 = EXP2(S4[kt][3]);
                if (need_mask) {
                    int key  = j0 + kt * 16 + quad * 4;
                    int qrow = rw + c;
                    if (key + 0 > qrow) p0 = 0.0f;
                    if (key + 1 > qrow) p1 = 0.0f;
                    if (key + 2 > qrow) p2 = 0.0f;
                    if (key + 3 > qrow) p3 = 0.0f;
                }
                uint2 pk;
                pk.x = cvtpk(p0, p1);
                pk.y = cvtpk(p2, p3);
                *(uint2*)(Pw + c * LDSW + kt * 16 + quad * 4) = pk;
            }

            // O += P V ; l += P * ones   (A from Pw[q][key], B from Vs[d][key])
            __builtin_amdgcn_s_setprio(1);
            #pragma unroll
            for (int ks = 0; ks < 2; ks++) {
                bf16x8 Af = *(const bf16x8*)(Pw + c * LDSW + ks * 32 + quad * 8);
                lacc = __builtin_amdgcn_mfma_f32_16x16x32_bf16(Af, ones, lacc, 0, 0, 0);
                #pragma unroll
                for (int dt = 0; dt < 4; dt++) {
                    bf16x8 Vf = *(const bf16x8*)(Vc + (dt * 16 + c) * LDSW + ks * 32 + quad * 8);
                    O[dt] = __builtin_amdgcn_mfma_f32_16x16x32_bf16(Af, Vf, O[dt], 0, 0, 0);
                }
            }
            __builtin_amdgcn_s_setprio(0);
        }
    }

    // normalize: l lands in C-layout rows (quad*4+e) == O's rows; no cross-lane needed
    float inv[4];
    #pragma unroll
    for (int e = 0; e < 4; e++) inv[e] = 1.0f / lacc[e];

    // O -> wave-private LDS region (aliases Pw) -> coalesced b128 global
    #pragma unroll
    for (int dt = 0; dt < 4; dt++)
        #pragma unroll
        for (int e = 0; e < 4; e++)
            Ps[(wave * 16 + quad * 4 + e) * LDSW + dt * 16 + c] = f2bf(O[dt][e] * inv[e]);
    __syncthreads();
    #pragma unroll
    for (int p = 0; p < 2; p++) {
        int r = p * 64 + sr;
        *(uint4*)(ao + ((size_t)(b * S_LEN + r0 + r)) * EMB + h * HD + scg) =
            *(const uint4*)(Ps + r * LDSW + scg);
    }
}

// ---------------- launch ----------------
extern "C" void kernel_launch(void* const* d_in, const int* in_sizes, int n_in,
                              void* d_out, int out_size, void* d_ws, size_t ws_size,
                              hipStream_t stream) {
    const float* x     = (const float*)d_in[0];
    const float* wq    = (const float*)d_in[1];
    const float* wk    = (const float*)d_in[2];
    const float* wv    = (const float*)d_in[3];
    const float* wproj = (const float*)d_in[4];
    const float* bproj = (const float*)d_in[5];
    float* out = (float*)d_out;

    char* ws = (char*)d_ws;
    unsigned short* wcat = (unsigned short*)(ws + 0);          //  6 MB  [3072,1024] (B^T)
    unsigned short* qb   = (unsigned short*)(ws + 8388608);    //  8 MB  [B,H,S,D] (x QSCALE)
    unsigned short* kb   = (unsigned short*)(ws + 16777216);   //  8 MB  [B,H,S,D]
    unsigned short* vt   = (unsigned short*)(ws + 25165824);   //  8 MB  [B,H,D,S]
    unsigned short* ao   = (unsigned short*)(ws + 33554432);   //  8 MB  [4096,1024]

    prep_wcat<<<384, 256, 0, stream>>>(wq, wk, wv, wcat);
    gemm_qkv<<<dim3(32, 24), 256, 0, stream>>>(x, wcat, qb, kb, vt);
    attn_mfma<<<512, 512, 0, stream>>>(qb, kb, vt, ao);
    gemm_proj<<<dim3(32, 8), 256, 0, stream>>>(ao, wproj, bproj, out);
}

// Round 9
// 195.337 us; speedup vs baseline: 1.3760x; 1.3760x over previous
//
#include <hip/hip_runtime.h>
#include <hip/hip_bf16.h>

// Problem: MultiHeadAttention  B=2,S=2048,E=1024,H=16,D=64
// R13: consolidation to the best measured config (R9 = 180.1us) after the
//     dbuf-GEMM experiment failed twice (R6: 390MB spill; R12: rule#20
//     runtime-indexed LDS ptr array -> 57MB spill + 73.7KB LDS -> 19% occ).
//     The 128^2 2-barrier core at 3 blocks/CU is the local optimum for K=1024.
//     Components: fused prep (casts+wcat) / R4-exact GEMM core (bf16 in) /
//     R9-exact attn (dbuf K/V, 1 barrier/tile) + validated cvtpk.
//     ONE experiment: gemm_proj M-split to 64-row tiles -> grid (64,8)=512
//     blocks = 2 blocks/CU (was 1), LDS 27.6KB. Occupancy-motivated.

typedef __attribute__((ext_vector_type(4))) float  f32x4;
typedef __attribute__((ext_vector_type(8))) short  bf16x8;

#define S_LEN 2048
#define EMB   1024
#define NH    16
#define HD    64

#define LDSW 72   // 64 + 8 pad: 144B row stride -- KEEP multiple of 8 shorts
                  // (16B) or every ds_*_b128 goes through the misaligned slow
                  // path (R8: 3x slowdown, zero reported conflicts).

// q pre-scale folds 1/sqrt(64) and log2(e):  0.125 * 1.4426950408889634
#define QSCALE 0.18033688011112042f

#if __has_builtin(__builtin_amdgcn_exp2f)
#define EXP2(x) __builtin_amdgcn_exp2f(x)
#else
#define EXP2(x) __exp2f(x)
#endif

__device__ __forceinline__ unsigned short f2bf(float f) {
    __hip_bfloat16 h = __float2bfloat16(f);
    return __builtin_bit_cast(unsigned short, h);
}
// HW packed cvt f32x2 -> bf16x2 (RNE), gfx950: no builtin, asm only.
__device__ __forceinline__ unsigned int cvtpk(float lo, float hi) {
    unsigned int r;
    asm("v_cvt_pk_bf16_f32 %0, %1, %2" : "=v"(r) : "v"(lo), "v"(hi));
    return r;
}

// ---------------- fused prep: casts + wcat build ----------------
// blocks [0,4096)        : cast x        (4096*1024 floats)
// blocks [4096,5120)     : cast w_proj   (1024*1024 floats)
// blocks [5120,5504)     : build wcat^T
__global__ __launch_bounds__(256) void prep(const float* __restrict__ x,
                                            const float* __restrict__ wq,
                                            const float* __restrict__ wk,
                                            const float* __restrict__ wv,
                                            const float* __restrict__ wproj,
                                            unsigned short* __restrict__ xb,
                                            unsigned short* __restrict__ wpb,
                                            unsigned short* __restrict__ wcat) {
    int blk = blockIdx.x;
    if (blk < 5120) {
        const float* in = (blk < 4096) ? x : wproj;
        unsigned short* out = (blk < 4096) ? xb : wpb;
        int bb = (blk < 4096) ? blk : blk - 4096;
        int i = (bb * 256 + threadIdx.x) * 4;
        float4 v = *(const float4*)(in + i);
        uint2 pk;
        pk.x = cvtpk(v.x, v.y);
        pk.y = cvtpk(v.z, v.w);
        *(uint2*)(out + i) = pk;
    } else {
        int b2  = blk - 5120;
        int et  = b2 & 7;
        int h   = (b2 >> 3) & 15;
        int qkv = b2 >> 7;
        const float* w = (qkv == 0) ? wq : (qkv == 1) ? wk : wv;
        int t = threadIdx.x;
        int d = t & 63, es = t >> 6;
        int e0 = et * 128 + es * 32;

        unsigned short val[32];
        #pragma unroll
        for (int i = 0; i < 32; i++)
            val[i] = f2bf(w[(size_t)h * 65536 + (size_t)(e0 + i) * 64 + d]);

        size_t n = (size_t)qkv * 1024 + h * 64 + d;
        #pragma unroll
        for (int k = 0; k < 4; k++)
            *(uint4*)(wcat + n * 1024 + e0 + k * 8) = *(const uint4*)(val + k * 8);
    }
}

// ---------------- GEMM core: C[128x128] = A[M,K] * Bt[N,K]^T, bf16, fp32 acc ----
// R4 structure: padded [128][72] LDS, stage within phase (2 uint4 live max),
// 2 barriers per K-step. 3 blocks/CU TLP hides the staging round-trip.
__device__ __forceinline__ void gemm_tile_core(const unsigned short* __restrict__ A,
                                               const unsigned short* __restrict__ Bt,
                                               int K, int m0, int n0,
                                               unsigned short* As, unsigned short* Bs,
                                               f32x4 acc[4][4]) {
    const int t    = threadIdx.x;
    const int wave = t >> 6, lane = t & 63;
    const int wm   = (wave >> 1) * 64, wn = (wave & 1) * 64;
    const int lr   = lane & 15, quad = lane >> 4;
    const int sr   = t >> 3;             // 0..31
    const int sc   = (t & 7) * 8;        // bf16 col

    #pragma unroll
    for (int i = 0; i < 4; i++)
        #pragma unroll
        for (int j = 0; j < 4; j++) acc[i][j] = (f32x4)(0.0f);

    for (int k0 = 0; k0 < K; k0 += 64) {
        __syncthreads();
        #pragma unroll
        for (int p = 0; p < 4; ++p) {
            int r = p * 32 + sr;
            uint4 av = *(const uint4*)(A  + (size_t)(m0 + r) * K + k0 + sc);
            uint4 bv = *(const uint4*)(Bt + (size_t)(n0 + r) * K + k0 + sc);
            *(uint4*)(As + r * LDSW + sc) = av;
            *(uint4*)(Bs + r * LDSW + sc) = bv;
        }
        __syncthreads();
        #pragma unroll
        for (int kk = 0; kk < 64; kk += 32) {
            bf16x8 af[4], bfr[4];
            #pragma unroll
            for (int i = 0; i < 4; i++)
                af[i] = *(const bf16x8*)(As + (wm + i * 16 + lr) * LDSW + kk + quad * 8);
            #pragma unroll
            for (int j = 0; j < 4; j++)
                bfr[j] = *(const bf16x8*)(Bs + (wn + j * 16 + lr) * LDSW + kk + quad * 8);
            #pragma unroll
            for (int i = 0; i < 4; i++)
                #pragma unroll
                for (int j = 0; j < 4; j++)
                    acc[i][j] = __builtin_amdgcn_mfma_f32_16x16x32_bf16(af[i], bfr[j], acc[i][j], 0, 0, 0);
        }
    }
}

// GEMM1: QKV = x * Wcat.
//   Q (scaled) -> qb[bh][s][d], K -> kb[bh][s][d]  (both via LDS roundtrip, b128 out)
//   V -> LDS-transpose -> vt[bh][d][s] (b128 out)
__global__ __launch_bounds__(256) void gemm_qkv(const unsigned short* __restrict__ xb,
                                                const unsigned short* __restrict__ wcat,
                                                unsigned short* __restrict__ qb,
                                                unsigned short* __restrict__ kb,
                                                unsigned short* __restrict__ vt) {
    __shared__ unsigned short Smem[2 * 128 * LDSW];   // 36864B; Tb needs 34816B
    unsigned short* As = Smem;
    unsigned short* Bs = Smem + 128 * LDSW;
    f32x4 acc[4][4];
    int m0 = blockIdx.x * 128, n0 = blockIdx.y * 128;
    gemm_tile_core(xb, wcat, EMB, m0, n0, As, Bs, acc);

    int t = threadIdx.x, wave = t >> 6, lane = t & 63;
    int wm = (wave >> 1) * 64, wn = (wave & 1) * 64, lr = lane & 15, quad = lane >> 4;
    int b  = m0 >> 11;
    int s0 = m0 & 2047;
    unsigned short* Tb = Smem;                 // reuse: [128][136]

    if (n0 < 2048) {
        bool isQ = (n0 < 1024);
        unsigned short* dst = isQ ? qb : kb;
        float sc = isQ ? QSCALE : 1.0f;
        __syncthreads();                       // done reading As/Bs
        #pragma unroll
        for (int i = 0; i < 4; i++)
            #pragma unroll
            for (int j = 0; j < 4; j++)
                #pragma unroll
                for (int e = 0; e < 4; e++)
                    Tb[(wm + i * 16 + quad * 4 + e) * 136 + wn + j * 16 + lr] = f2bf(acc[i][j][e] * sc);
        __syncthreads();
        #pragma unroll
        for (int p = 0; p < 8; p++) {
            int r  = p * 16 + (t >> 4);
            int ch = (t & 15) * 8;
            int n  = n0 + ch;
            int h  = (n >> 6) & 15, d = ch & 63;
            *(uint4*)(dst + (((size_t)(b * NH + h)) * S_LEN + s0 + r) * HD + d) =
                *(const uint4*)(Tb + r * 136 + ch);
        }
    } else {
        // V: transpose in LDS, then coalesced rows of vt[bh][d][s]
        __syncthreads();
        #pragma unroll
        for (int i = 0; i < 4; i++)
            #pragma unroll
            for (int j = 0; j < 4; j++)
                #pragma unroll
                for (int e = 0; e < 4; e++)
                    Tb[(wn + j * 16 + lr) * 136 + (wm + i * 16 + quad * 4 + e)] = f2bf(acc[i][j][e]);
        __syncthreads();
        #pragma unroll
        for (int p = 0; p < 8; p++) {
            int nl  = p * 16 + (t >> 4);
            int n   = n0 + nl;
            int h   = (n >> 6) & 15, d = n & 63;
            int col = (t & 15) * 8;
            *(uint4*)(vt + (((size_t)(b * NH + h)) * HD + d) * S_LEN + s0 + col) =
                *(const uint4*)(Tb + nl * 136 + col);
        }
    }
}

// GEMM2: out = ao * w_proj^T + b.  64-row M-tiles: grid (64,8) = 512 blocks
// = 2 blocks/CU (was 1 at 128 tiles -> 4 waves/CU, no TLP). 4 waves, each
// 32 rows x 64 cols (acc[2][4]). LDS: A 64 rows + B 128 rows = 27648B.
__global__ __launch_bounds__(256) void gemm_proj(const unsigned short* __restrict__ ao,
                                                 const unsigned short* __restrict__ wpb,
                                                 const float* __restrict__ bproj,
                                                 float* __restrict__ out) {
    __shared__ unsigned short Smem[(64 + 128) * LDSW];
    unsigned short* As = Smem;                 // [64][72]
    unsigned short* Bs = Smem + 64 * LDSW;     // [128][72]
    const int K = EMB;
    int m0 = blockIdx.x * 64, n0 = blockIdx.y * 128;

    const int t    = threadIdx.x;
    const int wave = t >> 6, lane = t & 63;
    const int wm   = (wave >> 1) * 32, wn = (wave & 1) * 64;
    const int lr   = lane & 15, quad = lane >> 4;
    const int sr   = t >> 3;             // 0..31
    const int sc   = (t & 7) * 8;        // bf16 col

    f32x4 acc[2][4];
    #pragma unroll
    for (int i = 0; i < 2; i++)
        #pragma unroll
        for (int j = 0; j < 4; j++) acc[i][j] = (f32x4)(0.0f);

    for (int k0 = 0; k0 < K; k0 += 64) {
        __syncthreads();
        #pragma unroll
        for (int p = 0; p < 2; ++p) {      // A: 64 rows
            int r = p * 32 + sr;
            uint4 av = *(const uint4*)(ao + (size_t)(m0 + r) * K + k0 + sc);
            *(uint4*)(As + r * LDSW + sc) = av;
        }
        #pragma unroll
        for (int p = 0; p < 4; ++p) {      // B: 128 rows
            int r = p * 32 + sr;
            uint4 bv = *(const uint4*)(wpb + (size_t)(n0 + r) * K + k0 + sc);
            *(uint4*)(Bs + r * LDSW + sc) = bv;
        }
        __syncthreads();
        #pragma unroll
        for (int kk = 0; kk < 64; kk += 32) {
            bf16x8 af[2], bfr[4];
            #pragma unroll
            for (int i = 0; i < 2; i++)
                af[i] = *(const bf16x8*)(As + (wm + i * 16 + lr) * LDSW + kk + quad * 8);
            #pragma unroll
            for (int j = 0; j < 4; j++)
                bfr[j] = *(const bf16x8*)(Bs + (wn + j * 16 + lr) * LDSW + kk + quad * 8);
            #pragma unroll
            for (int i = 0; i < 2; i++)
                #pragma unroll
                for (int j = 0; j < 4; j++)
                    acc[i][j] = __builtin_amdgcn_mfma_f32_16x16x32_bf16(af[i], bfr[j], acc[i][j], 0, 0, 0);
        }
    }

    #pragma unroll
    for (int i = 0; i < 2; i++)
        #pragma unroll
        for (int j = 0; j < 4; j++) {
            int n = n0 + wn + j * 16 + lr;
            float bias = bproj[n];
            #pragma unroll
            for (int e = 0; e < 4; e++) {
                int m = m0 + wm + i * 16 + quad * 4 + e;
                out[(size_t)m * EMB + n] = acc[i][j][e] + bias;
            }
        }
}

// ---------------- MFMA flash attention, causal, S^T-swapped ----------------
// R9-exact: 512 blocks x 512 threads = 32 bh x 16 chunks of 128 rows; 8 waves
// x 16 rows. Heavy-first chunk order: CU hosts blocks c & c+256 = chunks
// {15-g, g} -> constant 34 tiles per CU. Double-buffered K/V LDS: ONE barrier
// per tile. Softmax: exp2(S) raw (constant exponent bias cancels in O/l);
// l via MFMA-vs-ones; P->bf16 via v_cvt_pk_bf16_f32.
__global__ __launch_bounds__(512) void attn_mfma(const unsigned short* __restrict__ qb,
                                                 const unsigned short* __restrict__ kb,
                                                 const unsigned short* __restrict__ vtb,
                                                 unsigned short* __restrict__ ao) {
    __shared__ unsigned short Ks[2][64 * LDSW];     // [buf][key][d]
    __shared__ unsigned short Vs[2][64 * LDSW];     // [buf][d][key]
    __shared__ unsigned short Ps[128 * LDSW];       // 8 waves x 16 rows [q][key]; reused as O buffer

    int bIdx = blockIdx.x;
    int bh   = bIdx & 31;
    int grp  = bIdx >> 5;
    int chunk = (grp < 8) ? (15 - grp) : (grp - 8);   // heavy chunks first
    int b = bh >> 4, h = bh & 15;
    int t = threadIdx.x, wave = t >> 6, lane = t & 63;
    int c = lane & 15, quad = lane >> 4;

    const unsigned short* Q  = qb  + (size_t)bh * S_LEN * HD;
    const unsigned short* K  = kb  + (size_t)bh * S_LEN * HD;
    const unsigned short* Vt = vtb + (size_t)bh * HD * S_LEN;

    int r0 = chunk * 128;
    int rw = r0 + wave * 16;                 // wave's 16 q rows

    // Q frags (B-operand): B[n=q=c][k=d]
    bf16x8 Qf[2];
    #pragma unroll
    for (int ks = 0; ks < 2; ks++)
        Qf[ks] = *(const bf16x8*)(Q + (size_t)(rw + c) * HD + ks * 32 + quad * 8);

    f32x4 O[4];
    f32x4 lacc = (f32x4)(0.0f);
    #pragma unroll
    for (int dt = 0; dt < 4; dt++) O[dt] = (f32x4)(0.0f);

    const short oneb = (short)0x3F80;
    bf16x8 ones = {oneb, oneb, oneb, oneb, oneb, oneb, oneb, oneb};

    unsigned short* Pw = Ps + wave * 16 * LDSW;
    int sr = t >> 3, scg = (t & 7) * 8;      // 512 thr: sr 0..63

    int NT = (r0 + 128) >> 6;                // tiles this block computes (>= 2)

    // prologue: stage tile 0 directly, load tile 1 into regs
    uint4 kpre = *(const uint4*)(K  + (size_t)sr * HD + scg);
    uint4 vpre = *(const uint4*)(Vt + (size_t)sr * S_LEN + scg);
    *(uint4*)(Ks[0] + sr * LDSW + scg) = kpre;
    *(uint4*)(Vs[0] + sr * LDSW + scg) = vpre;
    kpre = *(const uint4*)(K  + (size_t)(64 + sr) * HD + scg);
    vpre = *(const uint4*)(Vt + (size_t)sr * S_LEN + 64 + scg);

    for (int tt = 0; tt < NT; ++tt) {
        __syncthreads();   // tile tt visible; tile tt-1 readers done
        if (tt + 1 < NT) {
            unsigned short* Kd = Ks[(tt + 1) & 1];
            unsigned short* Vd = Vs[(tt + 1) & 1];
            *(uint4*)(Kd + sr * LDSW + scg) = kpre;
            *(uint4*)(Vd + sr * LDSW + scg) = vpre;
            if (tt + 2 < NT) {
                kpre = *(const uint4*)(K  + (size_t)((tt + 2) * 64 + sr) * HD + scg);
                vpre = *(const uint4*)(Vt + (size_t)sr * S_LEN + (tt + 2) * 64 + scg);
            }
        }
        int j0 = tt << 6;
        if (j0 <= rw + 15) {
            const unsigned short* Kc = Ks[tt & 1];
            const unsigned short* Vc = Vs[tt & 1];

            // S^T = K Q^T : D[m=key][n=q]
            f32x4 S4[4];
            #pragma unroll
            for (int kt = 0; kt < 4; kt++) S4[kt] = (f32x4)(0.0f);
            __builtin_amdgcn_s_setprio(1);
            #pragma unroll
            for (int ks = 0; ks < 2; ks++) {
                bf16x8 Kf[4];
                #pragma unroll
                for (int kt = 0; kt < 4; kt++)
                    Kf[kt] = *(const bf16x8*)(Kc + (kt * 16 + c) * LDSW + ks * 32 + quad * 8);
                #pragma unroll
                for (int kt = 0; kt < 4; kt++)
                    S4[kt] = __builtin_amdgcn_mfma_f32_16x16x32_bf16(Kf[kt], Qf[ks], S4[kt], 0, 0, 0);
            }
            __builtin_amdgcn_s_setprio(0);

            bool need_mask = (j0 + 63 > rw);
            #pragma unroll
            for (int kt = 0; kt < 4; kt++) {
                float p0 = EXP2(S4[kt][0]);
                float p1 = EXP2(S4[kt][1]);
                float p2 = EXP2(S4[kt][2]);
                float p3 = EXP2(S4[kt][3]);
                if (need_mask) {
                    int key  = j0 + kt * 16 + quad * 4;
                    int qrow = rw + c;
                    if (key + 0 > qrow) p0 = 0.0f;
                    if (key + 1 > qrow) p1 = 0.0f;
                    if (key + 2 > qrow) p2 = 0.0f;
                    if (key + 3 > qrow) p3 = 0.0f;
                }
                uint2 pk;
                pk.x = cvtpk(p0, p1);
                pk.y = cvtpk(p2, p3);
                *(uint2*)(Pw + c * LDSW + kt * 16 + quad * 4) = pk;
            }

            // O += P V ; l += P * ones   (A from Pw[q][key], B from Vs[d][key])
            __builtin_amdgcn_s_setprio(1);
            #pragma unroll
            for (int ks = 0; ks < 2; ks++) {
                bf16x8 Af = *(const bf16x8*)(Pw + c * LDSW + ks * 32 + quad * 8);
                lacc = __builtin_amdgcn_mfma_f32_16x16x32_bf16(Af, ones, lacc, 0, 0, 0);
                #pragma unroll
                for (int dt = 0; dt < 4; dt++) {
                    bf16x8 Vf = *(const bf16x8*)(Vc + (dt * 16 + c) * LDSW + ks * 32 + quad * 8);
                    O[dt] = __builtin_amdgcn_mfma_f32_16x16x32_bf16(Af, Vf, O[dt], 0, 0, 0);
                }
            }
            __builtin_amdgcn_s_setprio(0);
        }
    }

    // normalize: l lands in C-layout rows (quad*4+e) == O's rows; no cross-lane needed
    float inv[4];
    #pragma unroll
    for (int e = 0; e < 4; e++) inv[e] = 1.0f / lacc[e];

    // O -> wave-private LDS region (aliases Pw) -> coalesced b128 global
    #pragma unroll
    for (int dt = 0; dt < 4; dt++)
        #pragma unroll
        for (int e = 0; e < 4; e++)
            Ps[(wave * 16 + quad * 4 + e) * LDSW + dt * 16 + c] = f2bf(O[dt][e] * inv[e]);
    __syncthreads();
    #pragma unroll
    for (int p = 0; p < 2; p++) {
        int r = p * 64 + sr;
        *(uint4*)(ao + ((size_t)(b * S_LEN + r0 + r)) * EMB + h * HD + scg) =
            *(const uint4*)(Ps + r * LDSW + scg);
    }
}

// ---------------- launch ----------------
extern "C" void kernel_launch(void* const* d_in, const int* in_sizes, int n_in,
                              void* d_out, int out_size, void* d_ws, size_t ws_size,
                              hipStream_t stream) {
    const float* x     = (const float*)d_in[0];
    const float* wq    = (const float*)d_in[1];
    const float* wk    = (const float*)d_in[2];
    const float* wv    = (const float*)d_in[3];
    const float* wproj = (const float*)d_in[4];
    const float* bproj = (const float*)d_in[5];
    float* out = (float*)d_out;

    char* ws = (char*)d_ws;
    unsigned short* xb   = (unsigned short*)(ws + 0);          //  8 MB  [4096,1024]
    unsigned short* wcat = (unsigned short*)(ws + 8388608);    //  6 MB  [3072,1024] (B^T)
    unsigned short* wpb  = (unsigned short*)(ws + 14680064);   //  2 MB  [1024,1024] (B^T)
    unsigned short* qb   = (unsigned short*)(ws + 16777216);   //  8 MB  [B,H,S,D] (x QSCALE)
    unsigned short* kb   = (unsigned short*)(ws + 25165824);   //  8 MB  [B,H,S,D]
    unsigned short* vt   = (unsigned short*)(ws + 33554432);   //  8 MB  [B,H,D,S]
    unsigned short* ao   = (unsigned short*)(ws + 41943040);   //  8 MB  [4096,1024]

    prep<<<5504, 256, 0, stream>>>(x, wq, wk, wv, wproj, xb, wpb, wcat);
    gemm_qkv<<<dim3(32, 24), 256, 0, stream>>>(xb, wcat, qb, kb, vt);
    attn_mfma<<<512, 512, 0, stream>>>(qb, kb, vt, ao);
    gemm_proj<<<dim3(64, 8), 256, 0, stream>>>(ao, wpb, bproj, out);
}

// Round 10
// 182.939 us; speedup vs baseline: 1.4693x; 1.0678x over previous
//
#include <hip/hip_runtime.h>
#include <hip/hip_bf16.h>

// Problem: MultiHeadAttention  B=2,S=2048,E=1024,H=16,D=64
// R14: revert to the measured-best configuration (R9 = 180.1us).
//     - gemm_proj back to 128x128 tiles, grid (32,8) (R13's 64-row M-split
//       regressed: staging:compute ratio 0.25->0.375, B traffic 2x).
//     - prep keeps R13's vectorized uint2 cast-store (strictly >= R9's
//       4 scalar stores).
//     - attn: R9-exact (dbuf K/V, 1 barrier/tile, exp2 unbiased, cvtpk,
//       heavy+light chunk pairing -> constant 34 tiles/CU).
//     - GEMM core: R4-exact 2-barrier structure (proven local optimum for
//       K=1024 vs gload_lds/dbuf/prefetch variants, R5-R12 evidence).

typedef __attribute__((ext_vector_type(4))) float  f32x4;
typedef __attribute__((ext_vector_type(8))) short  bf16x8;

#define S_LEN 2048
#define EMB   1024
#define NH    16
#define HD    64

#define LDSW 72   // 64 + 8 pad: 144B row stride -- KEEP multiple of 8 shorts
                  // (16B) or every ds_*_b128 goes through the misaligned slow
                  // path (R8: 3x slowdown, zero reported conflicts).

// q pre-scale folds 1/sqrt(64) and log2(e):  0.125 * 1.4426950408889634
#define QSCALE 0.18033688011112042f

#if __has_builtin(__builtin_amdgcn_exp2f)
#define EXP2(x) __builtin_amdgcn_exp2f(x)
#else
#define EXP2(x) __exp2f(x)
#endif

__device__ __forceinline__ unsigned short f2bf(float f) {
    __hip_bfloat16 h = __float2bfloat16(f);
    return __builtin_bit_cast(unsigned short, h);
}
// HW packed cvt f32x2 -> bf16x2 (RNE), gfx950: no builtin, asm only.
__device__ __forceinline__ unsigned int cvtpk(float lo, float hi) {
    unsigned int r;
    asm("v_cvt_pk_bf16_f32 %0, %1, %2" : "=v"(r) : "v"(lo), "v"(hi));
    return r;
}

// ---------------- fused prep: casts + wcat build ----------------
// blocks [0,4096)        : cast x        (4096*1024 floats)
// blocks [4096,5120)     : cast w_proj   (1024*1024 floats)
// blocks [5120,5504)     : build wcat^T
__global__ __launch_bounds__(256) void prep(const float* __restrict__ x,
                                            const float* __restrict__ wq,
                                            const float* __restrict__ wk,
                                            const float* __restrict__ wv,
                                            const float* __restrict__ wproj,
                                            unsigned short* __restrict__ xb,
                                            unsigned short* __restrict__ wpb,
                                            unsigned short* __restrict__ wcat) {
    int blk = blockIdx.x;
    if (blk < 5120) {
        const float* in = (blk < 4096) ? x : wproj;
        unsigned short* out = (blk < 4096) ? xb : wpb;
        int bb = (blk < 4096) ? blk : blk - 4096;
        int i = (bb * 256 + threadIdx.x) * 4;
        float4 v = *(const float4*)(in + i);
        uint2 pk;
        pk.x = cvtpk(v.x, v.y);
        pk.y = cvtpk(v.z, v.w);
        *(uint2*)(out + i) = pk;
    } else {
        int b2  = blk - 5120;
        int et  = b2 & 7;
        int h   = (b2 >> 3) & 15;
        int qkv = b2 >> 7;
        const float* w = (qkv == 0) ? wq : (qkv == 1) ? wk : wv;
        int t = threadIdx.x;
        int d = t & 63, es = t >> 6;
        int e0 = et * 128 + es * 32;

        unsigned short val[32];
        #pragma unroll
        for (int i = 0; i < 32; i++)
            val[i] = f2bf(w[(size_t)h * 65536 + (size_t)(e0 + i) * 64 + d]);

        size_t n = (size_t)qkv * 1024 + h * 64 + d;
        #pragma unroll
        for (int k = 0; k < 4; k++)
            *(uint4*)(wcat + n * 1024 + e0 + k * 8) = *(const uint4*)(val + k * 8);
    }
}

// ---------------- GEMM core: C[128x128] = A[M,K] * Bt[N,K]^T, bf16, fp32 acc ----
// R4 structure: padded [128][72] LDS, stage within phase (2 uint4 live max),
// 2 barriers per K-step. 3 blocks/CU TLP hides the staging round-trip.
__device__ __forceinline__ void gemm_tile_core(const unsigned short* __restrict__ A,
                                               const unsigned short* __restrict__ Bt,
                                               int K, int m0, int n0,
                                               unsigned short* As, unsigned short* Bs,
                                               f32x4 acc[4][4]) {
    const int t    = threadIdx.x;
    const int wave = t >> 6, lane = t & 63;
    const int wm   = (wave >> 1) * 64, wn = (wave & 1) * 64;
    const int lr   = lane & 15, quad = lane >> 4;
    const int sr   = t >> 3;             // 0..31
    const int sc   = (t & 7) * 8;        // bf16 col

    #pragma unroll
    for (int i = 0; i < 4; i++)
        #pragma unroll
        for (int j = 0; j < 4; j++) acc[i][j] = (f32x4)(0.0f);

    for (int k0 = 0; k0 < K; k0 += 64) {
        __syncthreads();
        #pragma unroll
        for (int p = 0; p < 4; ++p) {
            int r = p * 32 + sr;
            uint4 av = *(const uint4*)(A  + (size_t)(m0 + r) * K + k0 + sc);
            uint4 bv = *(const uint4*)(Bt + (size_t)(n0 + r) * K + k0 + sc);
            *(uint4*)(As + r * LDSW + sc) = av;
            *(uint4*)(Bs + r * LDSW + sc) = bv;
        }
        __syncthreads();
        #pragma unroll
        for (int kk = 0; kk < 64; kk += 32) {
            bf16x8 af[4], bfr[4];
            #pragma unroll
            for (int i = 0; i < 4; i++)
                af[i] = *(const bf16x8*)(As + (wm + i * 16 + lr) * LDSW + kk + quad * 8);
            #pragma unroll
            for (int j = 0; j < 4; j++)
                bfr[j] = *(const bf16x8*)(Bs + (wn + j * 16 + lr) * LDSW + kk + quad * 8);
            #pragma unroll
            for (int i = 0; i < 4; i++)
                #pragma unroll
                for (int j = 0; j < 4; j++)
                    acc[i][j] = __builtin_amdgcn_mfma_f32_16x16x32_bf16(af[i], bfr[j], acc[i][j], 0, 0, 0);
        }
    }
}

// GEMM1: QKV = x * Wcat.
//   Q (scaled) -> qb[bh][s][d], K -> kb[bh][s][d]  (both via LDS roundtrip, b128 out)
//   V -> LDS-transpose -> vt[bh][d][s] (b128 out)
__global__ __launch_bounds__(256) void gemm_qkv(const unsigned short* __restrict__ xb,
                                                const unsigned short* __restrict__ wcat,
                                                unsigned short* __restrict__ qb,
                                                unsigned short* __restrict__ kb,
                                                unsigned short* __restrict__ vt) {
    __shared__ unsigned short Smem[2 * 128 * LDSW];   // 36864B; Tb needs 34816B
    unsigned short* As = Smem;
    unsigned short* Bs = Smem + 128 * LDSW;
    f32x4 acc[4][4];
    int m0 = blockIdx.x * 128, n0 = blockIdx.y * 128;
    gemm_tile_core(xb, wcat, EMB, m0, n0, As, Bs, acc);

    int t = threadIdx.x, wave = t >> 6, lane = t & 63;
    int wm = (wave >> 1) * 64, wn = (wave & 1) * 64, lr = lane & 15, quad = lane >> 4;
    int b  = m0 >> 11;
    int s0 = m0 & 2047;
    unsigned short* Tb = Smem;                 // reuse: [128][136]

    if (n0 < 2048) {
        bool isQ = (n0 < 1024);
        unsigned short* dst = isQ ? qb : kb;
        float sc = isQ ? QSCALE : 1.0f;
        __syncthreads();                       // done reading As/Bs
        #pragma unroll
        for (int i = 0; i < 4; i++)
            #pragma unroll
            for (int j = 0; j < 4; j++)
                #pragma unroll
                for (int e = 0; e < 4; e++)
                    Tb[(wm + i * 16 + quad * 4 + e) * 136 + wn + j * 16 + lr] = f2bf(acc[i][j][e] * sc);
        __syncthreads();
        #pragma unroll
        for (int p = 0; p < 8; p++) {
            int r  = p * 16 + (t >> 4);
            int ch = (t & 15) * 8;
            int n  = n0 + ch;
            int h  = (n >> 6) & 15, d = ch & 63;
            *(uint4*)(dst + (((size_t)(b * NH + h)) * S_LEN + s0 + r) * HD + d) =
                *(const uint4*)(Tb + r * 136 + ch);
        }
    } else {
        // V: transpose in LDS, then coalesced rows of vt[bh][d][s]
        __syncthreads();
        #pragma unroll
        for (int i = 0; i < 4; i++)
            #pragma unroll
            for (int j = 0; j < 4; j++)
                #pragma unroll
                for (int e = 0; e < 4; e++)
                    Tb[(wn + j * 16 + lr) * 136 + (wm + i * 16 + quad * 4 + e)] = f2bf(acc[i][j][e]);
        __syncthreads();
        #pragma unroll
        for (int p = 0; p < 8; p++) {
            int nl  = p * 16 + (t >> 4);
            int n   = n0 + nl;
            int h   = (n >> 6) & 15, d = n & 63;
            int col = (t & 15) * 8;
            *(uint4*)(vt + (((size_t)(b * NH + h)) * HD + d) * S_LEN + s0 + col) =
                *(const uint4*)(Tb + nl * 136 + col);
        }
    }
}

// GEMM2: out = ao * w_proj^T + b   (128x128 tiles, grid (32,8) -- R9-exact)
__global__ __launch_bounds__(256) void gemm_proj(const unsigned short* __restrict__ ao,
                                                 const unsigned short* __restrict__ wpb,
                                                 const float* __restrict__ bproj,
                                                 float* __restrict__ out) {
    __shared__ unsigned short Smem[2 * 128 * LDSW];
    f32x4 acc[4][4];
    int m0 = blockIdx.x * 128, n0 = blockIdx.y * 128;
    gemm_tile_core(ao, wpb, EMB, m0, n0, Smem, Smem + 128 * LDSW, acc);

    int t = threadIdx.x, wave = t >> 6, lane = t & 63;
    int wm = (wave >> 1) * 64, wn = (wave & 1) * 64, lr = lane & 15, quad = lane >> 4;
    #pragma unroll
    for (int i = 0; i < 4; i++)
        #pragma unroll
        for (int j = 0; j < 4; j++) {
            int n = n0 + wn + j * 16 + lr;
            float bias = bproj[n];
            #pragma unroll
            for (int e = 0; e < 4; e++) {
                int m = m0 + wm + i * 16 + quad * 4 + e;
                out[(size_t)m * EMB + n] = acc[i][j][e] + bias;
            }
        }
}

// ---------------- MFMA flash attention, causal, S^T-swapped ----------------
// R9-exact: 512 blocks x 512 threads = 32 bh x 16 chunks of 128 rows; 8 waves
// x 16 rows. Heavy-first chunk order: CU hosts blocks c & c+256 = chunks
// {15-g, g} -> constant 34 tiles per CU. Double-buffered K/V LDS: ONE barrier
// per tile. Softmax: exp2(S) raw (constant exponent bias cancels in O/l);
// l via MFMA-vs-ones; P->bf16 via v_cvt_pk_bf16_f32.
__global__ __launch_bounds__(512) void attn_mfma(const unsigned short* __restrict__ qb,
                                                 const unsigned short* __restrict__ kb,
                                                 const unsigned short* __restrict__ vtb,
                                                 unsigned short* __restrict__ ao) {
    __shared__ unsigned short Ks[2][64 * LDSW];     // [buf][key][d]
    __shared__ unsigned short Vs[2][64 * LDSW];     // [buf][d][key]
    __shared__ unsigned short Ps[128 * LDSW];       // 8 waves x 16 rows [q][key]; reused as O buffer

    int bIdx = blockIdx.x;
    int bh   = bIdx & 31;
    int grp  = bIdx >> 5;
    int chunk = (grp < 8) ? (15 - grp) : (grp - 8);   // heavy chunks first
    int b = bh >> 4, h = bh & 15;
    int t = threadIdx.x, wave = t >> 6, lane = t & 63;
    int c = lane & 15, quad = lane >> 4;

    const unsigned short* Q  = qb  + (size_t)bh * S_LEN * HD;
    const unsigned short* K  = kb  + (size_t)bh * S_LEN * HD;
    const unsigned short* Vt = vtb + (size_t)bh * HD * S_LEN;

    int r0 = chunk * 128;
    int rw = r0 + wave * 16;                 // wave's 16 q rows

    // Q frags (B-operand): B[n=q=c][k=d]
    bf16x8 Qf[2];
    #pragma unroll
    for (int ks = 0; ks < 2; ks++)
        Qf[ks] = *(const bf16x8*)(Q + (size_t)(rw + c) * HD + ks * 32 + quad * 8);

    f32x4 O[4];
    f32x4 lacc = (f32x4)(0.0f);
    #pragma unroll
    for (int dt = 0; dt < 4; dt++) O[dt] = (f32x4)(0.0f);

    const short oneb = (short)0x3F80;
    bf16x8 ones = {oneb, oneb, oneb, oneb, oneb, oneb, oneb, oneb};

    unsigned short* Pw = Ps + wave * 16 * LDSW;
    int sr = t >> 3, scg = (t & 7) * 8;      // 512 thr: sr 0..63

    int NT = (r0 + 128) >> 6;                // tiles this block computes (>= 2)

    // prologue: stage tile 0 directly, load tile 1 into regs
    uint4 kpre = *(const uint4*)(K  + (size_t)sr * HD + scg);
    uint4 vpre = *(const uint4*)(Vt + (size_t)sr * S_LEN + scg);
    *(uint4*)(Ks[0] + sr * LDSW + scg) = kpre;
    *(uint4*)(Vs[0] + sr * LDSW + scg) = vpre;
    kpre = *(const uint4*)(K  + (size_t)(64 + sr) * HD + scg);
    vpre = *(const uint4*)(Vt + (size_t)sr * S_LEN + 64 + scg);

    for (int tt = 0; tt < NT; ++tt) {
        __syncthreads();   // tile tt visible; tile tt-1 readers done
        if (tt + 1 < NT) {
            unsigned short* Kd = Ks[(tt + 1) & 1];
            unsigned short* Vd = Vs[(tt + 1) & 1];
            *(uint4*)(Kd + sr * LDSW + scg) = kpre;
            *(uint4*)(Vd + sr * LDSW + scg) = vpre;
            if (tt + 2 < NT) {
                kpre = *(const uint4*)(K  + (size_t)((tt + 2) * 64 + sr) * HD + scg);
                vpre = *(const uint4*)(Vt + (size_t)sr * S_LEN + (tt + 2) * 64 + scg);
            }
        }
        int j0 = tt << 6;
        if (j0 <= rw + 15) {
            const unsigned short* Kc = Ks[tt & 1];
            const unsigned short* Vc = Vs[tt & 1];

            // S^T = K Q^T : D[m=key][n=q]
            f32x4 S4[4];
            #pragma unroll
            for (int kt = 0; kt < 4; kt++) S4[kt] = (f32x4)(0.0f);
            __builtin_amdgcn_s_setprio(1);
            #pragma unroll
            for (int ks = 0; ks < 2; ks++) {
                bf16x8 Kf[4];
                #pragma unroll
                for (int kt = 0; kt < 4; kt++)
                    Kf[kt] = *(const bf16x8*)(Kc + (kt * 16 + c) * LDSW + ks * 32 + quad * 8);
                #pragma unroll
                for (int kt = 0; kt < 4; kt++)
                    S4[kt] = __builtin_amdgcn_mfma_f32_16x16x32_bf16(Kf[kt], Qf[ks], S4[kt], 0, 0, 0);
            }
            __builtin_amdgcn_s_setprio(0);

            bool need_mask = (j0 + 63 > rw);
            #pragma unroll
            for (int kt = 0; kt < 4; kt++) {
                float p0 = EXP2(S4[kt][0]);
                float p1 = EXP2(S4[kt][1]);
                float p2 = EXP2(S4[kt][2]);
                float p3 = EXP2(S4[kt][3]);
                if (need_mask) {
                    int key  = j0 + kt * 16 + quad * 4;
                    int qrow = rw + c;
                    if (key + 0 > qrow) p0 = 0.0f;
                    if (key + 1 > qrow) p1 = 0.0f;
                    if (key + 2 > qrow) p2 = 0.0f;
                    if (key + 3 > qrow) p3 = 0.0f;
                }
                uint2 pk;
                pk.x = cvtpk(p0, p1);
                pk.y = cvtpk(p2, p3);
                *(uint2*)(Pw + c * LDSW + kt * 16 + quad * 4) = pk;
            }

            // O += P V ; l += P * ones   (A from Pw[q][key], B from Vs[d][key])
            __builtin_amdgcn_s_setprio(1);
            #pragma unroll
            for (int ks = 0; ks < 2; ks++) {
                bf16x8 Af = *(const bf16x8*)(Pw + c * LDSW + ks * 32 + quad * 8);
                lacc = __builtin_amdgcn_mfma_f32_16x16x32_bf16(Af, ones, lacc, 0, 0, 0);
                #pragma unroll
                for (int dt = 0; dt < 4; dt++) {
                    bf16x8 Vf = *(const bf16x8*)(Vc + (dt * 16 + c) * LDSW + ks * 32 + quad * 8);
                    O[dt] = __builtin_amdgcn_mfma_f32_16x16x32_bf16(Af, Vf, O[dt], 0, 0, 0);
                }
            }
            __builtin_amdgcn_s_setprio(0);
        }
    }

    // normalize: l lands in C-layout rows (quad*4+e) == O's rows; no cross-lane needed
    float inv[4];
    #pragma unroll
    for (int e = 0; e < 4; e++) inv[e] = 1.0f / lacc[e];

    // O -> wave-private LDS region (aliases Pw) -> coalesced b128 global
    #pragma unroll
    for (int dt = 0; dt < 4; dt++)
        #pragma unroll
        for (int e = 0; e < 4; e++)
            Ps[(wave * 16 + quad * 4 + e) * LDSW + dt * 16 + c] = f2bf(O[dt][e] * inv[e]);
    __syncthreads();
    #pragma unroll
    for (int p = 0; p < 2; p++) {
        int r = p * 64 + sr;
        *(uint4*)(ao + ((size_t)(b * S_LEN + r0 + r)) * EMB + h * HD + scg) =
            *(const uint4*)(Ps + r * LDSW + scg);
    }
}

// ---------------- launch ----------------
extern "C" void kernel_launch(void* const* d_in, const int* in_sizes, int n_in,
                              void* d_out, int out_size, void* d_ws, size_t ws_size,
                              hipStream_t stream) {
    const float* x     = (const float*)d_in[0];
    const float* wq    = (const float*)d_in[1];
    const float* wk    = (const float*)d_in[2];
    const float* wv    = (const float*)d_in[3];
    const float* wproj = (const float*)d_in[4];
    const float* bproj = (const float*)d_in[5];
    float* out = (float*)d_out;

    char* ws = (char*)d_ws;
    unsigned short* xb   = (unsigned short*)(ws + 0);          //  8 MB  [4096,1024]
    unsigned short* wcat = (unsigned short*)(ws + 8388608);    //  6 MB  [3072,1024] (B^T)
    unsigned short* wpb  = (unsigned short*)(ws + 14680064);   //  2 MB  [1024,1024] (B^T)
    unsigned short* qb   = (unsigned short*)(ws + 16777216);   //  8 MB  [B,H,S,D] (x QSCALE)
    unsigned short* kb   = (unsigned short*)(ws + 25165824);   //  8 MB  [B,H,S,D]
    unsigned short* vt   = (unsigned short*)(ws + 33554432);   //  8 MB  [B,H,D,S]
    unsigned short* ao   = (unsigned short*)(ws + 41943040);   //  8 MB  [4096,1024]

    prep<<<5504, 256, 0, stream>>>(x, wq, wk, wv, wproj, xb, wpb, wcat);
    gemm_qkv<<<dim3(32, 24), 256, 0, stream>>>(xb, wcat, qb, kb, vt);
    attn_mfma<<<512, 512, 0, stream>>>(qb, kb, vt, ao);
    gemm_proj<<<dim3(32, 8), 256, 0, stream>>>(ao, wpb, bproj, out);
}

// Round 11
// 177.129 us; speedup vs baseline: 1.5175x; 1.0328x over previous
//
#include <hip/hip_runtime.h>
#include <hip/hip_bf16.h>

// Problem: MultiHeadAttention  B=2,S=2048,E=1024,H=16,D=64
// R15 (final): measured-best configuration, banked. 180-183us across four
// independent benches (R0/R3/R9/R14). Session ledger:
//   WINS:   attn dbuf K/V 1-barrier/tile (+4us), EXP2C-bias drop, cvtpk,
//           vectorized prep stores, fused prep (6->4 launches).
//   REFUTED: gload_lds@K=1024, reg-prefetch GEMM (spills: R6/R12),
//           LDS pad 68 (b128 misalign), L2-direct attn (gather latency),
//           q-reg-blocking + slab/proj splits (occupancy/ratio losses).
//   ANALYSIS: LDSW=72 fragment reads are conflict-free per 8-lane cycle
//           group (4c mod 32 slots); residual counter = cross-block noise.
//   Remaining gap is the co-designed 8-phase stack (T16-class rewrite),
//   not reachable by incremental grafts on this structure (each isolated
//   graft measured null/negative, matching the T-catalog dependency graph).

typedef __attribute__((ext_vector_type(4))) float  f32x4;
typedef __attribute__((ext_vector_type(8))) short  bf16x8;

#define S_LEN 2048
#define EMB   1024
#define NH    16
#define HD    64

#define LDSW 72   // 64 + 8 pad: 144B row stride -- KEEP multiple of 8 shorts
                  // (16B) or every ds_*_b128 goes through the misaligned slow
                  // path (R8: 3x slowdown, zero reported conflicts).

// q pre-scale folds 1/sqrt(64) and log2(e):  0.125 * 1.4426950408889634
#define QSCALE 0.18033688011112042f

#if __has_builtin(__builtin_amdgcn_exp2f)
#define EXP2(x) __builtin_amdgcn_exp2f(x)
#else
#define EXP2(x) __exp2f(x)
#endif

__device__ __forceinline__ unsigned short f2bf(float f) {
    __hip_bfloat16 h = __float2bfloat16(f);
    return __builtin_bit_cast(unsigned short, h);
}
// HW packed cvt f32x2 -> bf16x2 (RNE), gfx950: no builtin, asm only.
__device__ __forceinline__ unsigned int cvtpk(float lo, float hi) {
    unsigned int r;
    asm("v_cvt_pk_bf16_f32 %0, %1, %2" : "=v"(r) : "v"(lo), "v"(hi));
    return r;
}

// ---------------- fused prep: casts + wcat build ----------------
// blocks [0,4096)        : cast x        (4096*1024 floats)
// blocks [4096,5120)     : cast w_proj   (1024*1024 floats)
// blocks [5120,5504)     : build wcat^T
__global__ __launch_bounds__(256) void prep(const float* __restrict__ x,
                                            const float* __restrict__ wq,
                                            const float* __restrict__ wk,
                                            const float* __restrict__ wv,
                                            const float* __restrict__ wproj,
                                            unsigned short* __restrict__ xb,
                                            unsigned short* __restrict__ wpb,
                                            unsigned short* __restrict__ wcat) {
    int blk = blockIdx.x;
    if (blk < 5120) {
        const float* in = (blk < 4096) ? x : wproj;
        unsigned short* out = (blk < 4096) ? xb : wpb;
        int bb = (blk < 4096) ? blk : blk - 4096;
        int i = (bb * 256 + threadIdx.x) * 4;
        float4 v = *(const float4*)(in + i);
        uint2 pk;
        pk.x = cvtpk(v.x, v.y);
        pk.y = cvtpk(v.z, v.w);
        *(uint2*)(out + i) = pk;
    } else {
        int b2  = blk - 5120;
        int et  = b2 & 7;
        int h   = (b2 >> 3) & 15;
        int qkv = b2 >> 7;
        const float* w = (qkv == 0) ? wq : (qkv == 1) ? wk : wv;
        int t = threadIdx.x;
        int d = t & 63, es = t >> 6;
        int e0 = et * 128 + es * 32;

        unsigned short val[32];
        #pragma unroll
        for (int i = 0; i < 32; i++)
            val[i] = f2bf(w[(size_t)h * 65536 + (size_t)(e0 + i) * 64 + d]);

        size_t n = (size_t)qkv * 1024 + h * 64 + d;
        #pragma unroll
        for (int k = 0; k < 4; k++)
            *(uint4*)(wcat + n * 1024 + e0 + k * 8) = *(const uint4*)(val + k * 8);
    }
}

// ---------------- GEMM core: C[128x128] = A[M,K] * Bt[N,K]^T, bf16, fp32 acc ----
// R4 structure: padded [128][72] LDS, stage within phase (2 uint4 live max),
// 2 barriers per K-step. 3 blocks/CU TLP hides the staging round-trip.
// Proven local optimum for K=1024 vs gload_lds/dbuf/prefetch (R5-R12).
__device__ __forceinline__ void gemm_tile_core(const unsigned short* __restrict__ A,
                                               const unsigned short* __restrict__ Bt,
                                               int K, int m0, int n0,
                                               unsigned short* As, unsigned short* Bs,
                                               f32x4 acc[4][4]) {
    const int t    = threadIdx.x;
    const int wave = t >> 6, lane = t & 63;
    const int wm   = (wave >> 1) * 64, wn = (wave & 1) * 64;
    const int lr   = lane & 15, quad = lane >> 4;
    const int sr   = t >> 3;             // 0..31
    const int sc   = (t & 7) * 8;        // bf16 col

    #pragma unroll
    for (int i = 0; i < 4; i++)
        #pragma unroll
        for (int j = 0; j < 4; j++) acc[i][j] = (f32x4)(0.0f);

    for (int k0 = 0; k0 < K; k0 += 64) {
        __syncthreads();
        #pragma unroll
        for (int p = 0; p < 4; ++p) {
            int r = p * 32 + sr;
            uint4 av = *(const uint4*)(A  + (size_t)(m0 + r) * K + k0 + sc);
            uint4 bv = *(const uint4*)(Bt + (size_t)(n0 + r) * K + k0 + sc);
            *(uint4*)(As + r * LDSW + sc) = av;
            *(uint4*)(Bs + r * LDSW + sc) = bv;
        }
        __syncthreads();
        #pragma unroll
        for (int kk = 0; kk < 64; kk += 32) {
            bf16x8 af[4], bfr[4];
            #pragma unroll
            for (int i = 0; i < 4; i++)
                af[i] = *(const bf16x8*)(As + (wm + i * 16 + lr) * LDSW + kk + quad * 8);
            #pragma unroll
            for (int j = 0; j < 4; j++)
                bfr[j] = *(const bf16x8*)(Bs + (wn + j * 16 + lr) * LDSW + kk + quad * 8);
            #pragma unroll
            for (int i = 0; i < 4; i++)
                #pragma unroll
                for (int j = 0; j < 4; j++)
                    acc[i][j] = __builtin_amdgcn_mfma_f32_16x16x32_bf16(af[i], bfr[j], acc[i][j], 0, 0, 0);
        }
    }
}

// GEMM1: QKV = x * Wcat.
//   Q (scaled) -> qb[bh][s][d], K -> kb[bh][s][d]  (both via LDS roundtrip, b128 out)
//   V -> LDS-transpose -> vt[bh][d][s] (b128 out)
__global__ __launch_bounds__(256) void gemm_qkv(const unsigned short* __restrict__ xb,
                                                const unsigned short* __restrict__ wcat,
                                                unsigned short* __restrict__ qb,
                                                unsigned short* __restrict__ kb,
                                                unsigned short* __restrict__ vt) {
    __shared__ unsigned short Smem[2 * 128 * LDSW];   // 36864B; Tb needs 34816B
    unsigned short* As = Smem;
    unsigned short* Bs = Smem + 128 * LDSW;
    f32x4 acc[4][4];
    int m0 = blockIdx.x * 128, n0 = blockIdx.y * 128;
    gemm_tile_core(xb, wcat, EMB, m0, n0, As, Bs, acc);

    int t = threadIdx.x, wave = t >> 6, lane = t & 63;
    int wm = (wave >> 1) * 64, wn = (wave & 1) * 64, lr = lane & 15, quad = lane >> 4;
    int b  = m0 >> 11;
    int s0 = m0 & 2047;
    unsigned short* Tb = Smem;                 // reuse: [128][136]

    if (n0 < 2048) {
        bool isQ = (n0 < 1024);
        unsigned short* dst = isQ ? qb : kb;
        float sc = isQ ? QSCALE : 1.0f;
        __syncthreads();                       // done reading As/Bs
        #pragma unroll
        for (int i = 0; i < 4; i++)
            #pragma unroll
            for (int j = 0; j < 4; j++)
                #pragma unroll
                for (int e = 0; e < 4; e++)
                    Tb[(wm + i * 16 + quad * 4 + e) * 136 + wn + j * 16 + lr] = f2bf(acc[i][j][e] * sc);
        __syncthreads();
        #pragma unroll
        for (int p = 0; p < 8; p++) {
            int r  = p * 16 + (t >> 4);
            int ch = (t & 15) * 8;
            int n  = n0 + ch;
            int h  = (n >> 6) & 15, d = ch & 63;
            *(uint4*)(dst + (((size_t)(b * NH + h)) * S_LEN + s0 + r) * HD + d) =
                *(const uint4*)(Tb + r * 136 + ch);
        }
    } else {
        // V: transpose in LDS, then coalesced rows of vt[bh][d][s]
        __syncthreads();
        #pragma unroll
        for (int i = 0; i < 4; i++)
            #pragma unroll
            for (int j = 0; j < 4; j++)
                #pragma unroll
                for (int e = 0; e < 4; e++)
                    Tb[(wn + j * 16 + lr) * 136 + (wm + i * 16 + quad * 4 + e)] = f2bf(acc[i][j][e]);
        __syncthreads();
        #pragma unroll
        for (int p = 0; p < 8; p++) {
            int nl  = p * 16 + (t >> 4);
            int n   = n0 + nl;
            int h   = (n >> 6) & 15, d = n & 63;
            int col = (t & 15) * 8;
            *(uint4*)(vt + (((size_t)(b * NH + h)) * HD + d) * S_LEN + s0 + col) =
                *(const uint4*)(Tb + nl * 136 + col);
        }
    }
}

// GEMM2: out = ao * w_proj^T + b   (128x128 tiles, grid (32,8))
__global__ __launch_bounds__(256) void gemm_proj(const unsigned short* __restrict__ ao,
                                                 const unsigned short* __restrict__ wpb,
                                                 const float* __restrict__ bproj,
                                                 float* __restrict__ out) {
    __shared__ unsigned short Smem[2 * 128 * LDSW];
    f32x4 acc[4][4];
    int m0 = blockIdx.x * 128, n0 = blockIdx.y * 128;
    gemm_tile_core(ao, wpb, EMB, m0, n0, Smem, Smem + 128 * LDSW, acc);

    int t = threadIdx.x, wave = t >> 6, lane = t & 63;
    int wm = (wave >> 1) * 64, wn = (wave & 1) * 64, lr = lane & 15, quad = lane >> 4;
    #pragma unroll
    for (int i = 0; i < 4; i++)
        #pragma unroll
        for (int j = 0; j < 4; j++) {
            int n = n0 + wn + j * 16 + lr;
            float bias = bproj[n];
            #pragma unroll
            for (int e = 0; e < 4; e++) {
                int m = m0 + wm + i * 16 + quad * 4 + e;
                out[(size_t)m * EMB + n] = acc[i][j][e] + bias;
            }
        }
}

// ---------------- MFMA flash attention, causal, S^T-swapped ----------------
// 512 blocks x 512 threads = 32 bh x 16 chunks of 128 rows; 8 waves x 16 rows.
// Heavy-first chunk order: CU hosts blocks c & c+256 = chunks {15-g, g} ->
// constant 34 tiles per CU. Double-buffered K/V LDS: ONE barrier per tile.
// Softmax: exp2(S) raw (constant exponent bias cancels in O/l); l via
// MFMA-vs-ones (lands in C-layout rows aligned with O); P->bf16 via cvtpk.
__global__ __launch_bounds__(512) void attn_mfma(const unsigned short* __restrict__ qb,
                                                 const unsigned short* __restrict__ kb,
                                                 const unsigned short* __restrict__ vtb,
                                                 unsigned short* __restrict__ ao) {
    __shared__ unsigned short Ks[2][64 * LDSW];     // [buf][key][d]
    __shared__ unsigned short Vs[2][64 * LDSW];     // [buf][d][key]
    __shared__ unsigned short Ps[128 * LDSW];       // 8 waves x 16 rows [q][key]; reused as O buffer

    int bIdx = blockIdx.x;
    int bh   = bIdx & 31;
    int grp  = bIdx >> 5;
    int chunk = (grp < 8) ? (15 - grp) : (grp - 8);   // heavy chunks first
    int b = bh >> 4, h = bh & 15;
    int t = threadIdx.x, wave = t >> 6, lane = t & 63;
    int c = lane & 15, quad = lane >> 4;

    const unsigned short* Q  = qb  + (size_t)bh * S_LEN * HD;
    const unsigned short* K  = kb  + (size_t)bh * S_LEN * HD;
    const unsigned short* Vt = vtb + (size_t)bh * HD * S_LEN;

    int r0 = chunk * 128;
    int rw = r0 + wave * 16;                 // wave's 16 q rows

    // Q frags (B-operand): B[n=q=c][k=d]
    bf16x8 Qf[2];
    #pragma unroll
    for (int ks = 0; ks < 2; ks++)
        Qf[ks] = *(const bf16x8*)(Q + (size_t)(rw + c) * HD + ks * 32 + quad * 8);

    f32x4 O[4];
    f32x4 lacc = (f32x4)(0.0f);
    #pragma unroll
    for (int dt = 0; dt < 4; dt++) O[dt] = (f32x4)(0.0f);

    const short oneb = (short)0x3F80;
    bf16x8 ones = {oneb, oneb, oneb, oneb, oneb, oneb, oneb, oneb};

    unsigned short* Pw = Ps + wave * 16 * LDSW;
    int sr = t >> 3, scg = (t & 7) * 8;      // 512 thr: sr 0..63

    int NT = (r0 + 128) >> 6;                // tiles this block computes (>= 2)

    // prologue: stage tile 0 directly, load tile 1 into regs
    uint4 kpre = *(const uint4*)(K  + (size_t)sr * HD + scg);
    uint4 vpre = *(const uint4*)(Vt + (size_t)sr * S_LEN + scg);
    *(uint4*)(Ks[0] + sr * LDSW + scg) = kpre;
    *(uint4*)(Vs[0] + sr * LDSW + scg) = vpre;
    kpre = *(const uint4*)(K  + (size_t)(64 + sr) * HD + scg);
    vpre = *(const uint4*)(Vt + (size_t)sr * S_LEN + 64 + scg);

    for (int tt = 0; tt < NT; ++tt) {
        __syncthreads();   // tile tt visible; tile tt-1 readers done
        if (tt + 1 < NT) {
            unsigned short* Kd = Ks[(tt + 1) & 1];
            unsigned short* Vd = Vs[(tt + 1) & 1];
            *(uint4*)(Kd + sr * LDSW + scg) = kpre;
            *(uint4*)(Vd + sr * LDSW + scg) = vpre;
            if (tt + 2 < NT) {
                kpre = *(const uint4*)(K  + (size_t)((tt + 2) * 64 + sr) * HD + scg);
                vpre = *(const uint4*)(Vt + (size_t)sr * S_LEN + (tt + 2) * 64 + scg);
            }
        }
        int j0 = tt << 6;
        if (j0 <= rw + 15) {
            const unsigned short* Kc = Ks[tt & 1];
            const unsigned short* Vc = Vs[tt & 1];

            // S^T = K Q^T : D[m=key][n=q]
            f32x4 S4[4];
            #pragma unroll
            for (int kt = 0; kt < 4; kt++) S4[kt] = (f32x4)(0.0f);
            __builtin_amdgcn_s_setprio(1);
            #pragma unroll
            for (int ks = 0; ks < 2; ks++) {
                bf16x8 Kf[4];
                #pragma unroll
                for (int kt = 0; kt < 4; kt++)
                    Kf[kt] = *(const bf16x8*)(Kc + (kt * 16 + c) * LDSW + ks * 32 + quad * 8);
                #pragma unroll
                for (int kt = 0; kt < 4; kt++)
                    S4[kt] = __builtin_amdgcn_mfma_f32_16x16x32_bf16(Kf[kt], Qf[ks], S4[kt], 0, 0, 0);
            }
            __builtin_amdgcn_s_setprio(0);

            bool need_mask = (j0 + 63 > rw);
            #pragma unroll
            for (int kt = 0; kt < 4; kt++) {
                float p0 = EXP2(S4[kt][0]);
                float p1 = EXP2(S4[kt][1]);
                float p2 = EXP2(S4[kt][2]);
                float p3 = EXP2(S4[kt][3]);
                if (need_mask) {
                    int key  = j0 + kt * 16 + quad * 4;
                    int qrow = rw + c;
                    if (key + 0 > qrow) p0 = 0.0f;
                    if (key + 1 > qrow) p1 = 0.0f;
                    if (key + 2 > qrow) p2 = 0.0f;
                    if (key + 3 > qrow) p3 = 0.0f;
                }
                uint2 pk;
                pk.x = cvtpk(p0, p1);
                pk.y = cvtpk(p2, p3);
                *(uint2*)(Pw + c * LDSW + kt * 16 + quad * 4) = pk;
            }

            // O += P V ; l += P * ones   (A from Pw[q][key], B from Vs[d][key])
            __builtin_amdgcn_s_setprio(1);
            #pragma unroll
            for (int ks = 0; ks < 2; ks++) {
                bf16x8 Af = *(const bf16x8*)(Pw + c * LDSW + ks * 32 + quad * 8);
                lacc = __builtin_amdgcn_mfma_f32_16x16x32_bf16(Af, ones, lacc, 0, 0, 0);
                #pragma unroll
                for (int dt = 0; dt < 4; dt++) {
                    bf16x8 Vf = *(const bf16x8*)(Vc + (dt * 16 + c) * LDSW + ks * 32 + quad * 8);
                    O[dt] = __builtin_amdgcn_mfma_f32_16x16x32_bf16(Af, Vf, O[dt], 0, 0, 0);
                }
            }
            __builtin_amdgcn_s_setprio(0);
        }
    }

    // normalize: l lands in C-layout rows (quad*4+e) == O's rows; no cross-lane needed
    float inv[4];
    #pragma unroll
    for (int e = 0; e < 4; e++) inv[e] = 1.0f / lacc[e];

    // O -> wave-private LDS region (aliases Pw) -> coalesced b128 global
    #pragma unroll
    for (int dt = 0; dt < 4; dt++)
        #pragma unroll
        for (int e = 0; e < 4; e++)
            Ps[(wave * 16 + quad * 4 + e) * LDSW + dt * 16 + c] = f2bf(O[dt][e] * inv[e]);
    __syncthreads();
    #pragma unroll
    for (int p = 0; p < 2; p++) {
        int r = p * 64 + sr;
        *(uint4*)(ao + ((size_t)(b * S_LEN + r0 + r)) * EMB + h * HD + scg) =
            *(const uint4*)(Ps + r * LDSW + scg);
    }
}

// ---------------- launch ----------------
extern "C" void kernel_launch(void* const* d_in, const int* in_sizes, int n_in,
                              void* d_out, int out_size, void* d_ws, size_t ws_size,
                              hipStream_t stream) {
    const float* x     = (const float*)d_in[0];
    const float* wq    = (const float*)d_in[1];
    const float* wk    = (const float*)d_in[2];
    const float* wv    = (const float*)d_in[3];
    const float* wproj = (const float*)d_in[4];
    const float* bproj = (const float*)d_in[5];
    float* out = (float*)d_out;

    char* ws = (char*)d_ws;
    unsigned short* xb   = (unsigned short*)(ws + 0);          //  8 MB  [4096,1024]
    unsigned short* wcat = (unsigned short*)(ws + 8388608);    //  6 MB  [3072,1024] (B^T)
    unsigned short* wpb  = (unsigned short*)(ws + 14680064);   //  2 MB  [1024,1024] (B^T)
    unsigned short* qb   = (unsigned short*)(ws + 16777216);   //  8 MB  [B,H,S,D] (x QSCALE)
    unsigned short* kb   = (unsigned short*)(ws + 25165824);   //  8 MB  [B,H,S,D]
    unsigned short* vt   = (unsigned short*)(ws + 33554432);   //  8 MB  [B,H,D,S]
    unsigned short* ao   = (unsigned short*)(ws + 41943040);   //  8 MB  [4096,1024]

    prep<<<5504, 256, 0, stream>>>(x, wq, wk, wv, wproj, xb, wpb, wcat);
    gemm_qkv<<<dim3(32, 24), 256, 0, stream>>>(xb, wcat, qb, kb, vt);
    attn_mfma<<<512, 512, 0, stream>>>(qb, kb, vt, ao);
    gemm_proj<<<dim3(32, 8), 256, 0, stream>>>(ao, wpb, bproj, out);
}